// Round 7
// baseline (164.483 us; speedup 1.0000x reference)
//
#include <hip/hip_runtime.h>
#include <hip/hip_bf16.h>
#include <math.h>

typedef __hip_bfloat16 bf16;
typedef short v8s __attribute__((ext_vector_type(8)));
typedef float v4f __attribute__((ext_vector_type(4)));

#define B_TOK 4096
#define E_EXP 8
#define D_IN  768
#define D_H   2048
#define D_OUT 768
#define MAXT  40      // max M-tiles of 256 over all experts (32 + 7 skew, padded)

// ---------------------------------------------------------------- helpers
__device__ __forceinline__ void gl_lds16(const bf16* g, bf16* l) {
  __builtin_amdgcn_global_load_lds(
      (const __attribute__((address_space(1))) unsigned int*)g,
      (__attribute__((address_space(3))) unsigned int*)l, 16, 0, 0);
}

// ---------------------------------------------- fused x->bf16 + gating (no atomics)
__global__ void gate_cvt_kernel(const float* __restrict__ x, const float* __restrict__ wg,
                                bf16* __restrict__ xb,
                                float* __restrict__ gates, int* __restrict__ tidx) {
  int gt = blockIdx.x * 256 + threadIdx.x;
  int tok = gt >> 6, l = gt & 63;
  const float* xr = x + (size_t)tok * D_IN;
  bf16* xbr = xb + (size_t)tok * D_IN;
  float acc[8] = {0.f,0.f,0.f,0.f,0.f,0.f,0.f,0.f};
  #pragma unroll
  for (int i = 0; i < 3; ++i) {
    int k0 = i * 256 + l * 4;
    float4 v = *(const float4*)(xr + k0);
    union { bf16 h[4]; uint2 u; } pk;
    pk.h[0] = __float2bfloat16(v.x); pk.h[1] = __float2bfloat16(v.y);
    pk.h[2] = __float2bfloat16(v.z); pk.h[3] = __float2bfloat16(v.w);
    *(uint2*)(xbr + k0) = pk.u;
    float xv[4] = {v.x, v.y, v.z, v.w};
    #pragma unroll
    for (int j = 0; j < 4; ++j) {
      const float* wr = wg + (size_t)(k0 + j) * 8;
      float4 w0 = *(const float4*)wr;
      float4 w1 = *(const float4*)(wr + 4);
      acc[0] += xv[j] * w0.x; acc[1] += xv[j] * w0.y;
      acc[2] += xv[j] * w0.z; acc[3] += xv[j] * w0.w;
      acc[4] += xv[j] * w1.x; acc[5] += xv[j] * w1.y;
      acc[6] += xv[j] * w1.z; acc[7] += xv[j] * w1.w;
    }
  }
  #pragma unroll
  for (int d = 1; d < 64; d <<= 1)
    #pragma unroll
    for (int e = 0; e < 8; ++e) acc[e] += __shfl_xor(acc[e], d);
  if (l == 0) {
    int i1 = 0; float v1 = acc[0];
    #pragma unroll
    for (int e = 1; e < 8; ++e) if (acc[e] > v1) { v1 = acc[e]; i1 = e; }
    int i2 = -1; float v2 = -1e30f;
    #pragma unroll
    for (int e = 0; e < 8; ++e) if (e != i1 && acc[e] > v2) { v2 = acc[e]; i2 = e; }
    float ex = __expf(v2 - v1);
    float g1 = 1.f / (1.f + ex), g2 = ex / (1.f + ex);
    gates[2 * tok] = g1; gates[2 * tok + 1] = g2;
    tidx[2 * tok] = i1;  tidx[2 * tok + 1] = i2;
  }
}

// ---------------------------------------------- single-block: histogram + scan +
// slot assignment + counts/offsets + tile map + aux loss.  256 threads.
__global__ void finalize_kernel(const int* __restrict__ tidx, const float* __restrict__ gates,
                                int* __restrict__ cnt_off, int* __restrict__ row_ids,
                                int* __restrict__ pos, int* __restrict__ tmap,
                                float* __restrict__ loss_out) {
  __shared__ int   hcnt[256][9];
  __shared__ float himp[256][9];
  __shared__ int   tot[8], off[8];
  __shared__ float itot[8];
  int t = threadIdx.x;
  #pragma unroll
  for (int e = 0; e < 8; ++e) { hcnt[t][e] = 0; himp[t][e] = 0.f; }
  __syncthreads();
  for (int i = 0; i < 32; ++i) {
    int idx = t * 32 + i;
    int e = tidx[idx];
    hcnt[t][e] += 1;
    himp[t][e] += gates[idx];
  }
  __syncthreads();
  if (t < 8) {
    int run = 0; float s = 0.f;
    for (int j = 0; j < 256; ++j) {
      int c = hcnt[j][t];
      hcnt[j][t] = run;
      run += c;
      s += himp[j][t];
    }
    tot[t] = run; itot[t] = s;
  }
  __syncthreads();
  if (t == 0) {
    int o = 0;
    float mi = 0.f, ml = 0.f;
    for (int e = 0; e < 8; ++e) {
      off[e] = o; o += tot[e];
      cnt_off[e] = tot[e]; cnt_off[8 + e] = off[e];
      mi += itot[e]; ml += (float)tot[e];
    }
    mi *= 0.125f; ml *= 0.125f;
    float vi = 0.f, vl = 0.f;
    for (int e = 0; e < 8; ++e) {
      float d = itot[e] - mi;        vi += d * d;
      float d2 = (float)tot[e] - ml; vl += d2 * d2;
    }
    vi /= 7.f; vl /= 7.f;
    *loss_out = 0.01f * (vi / (mi * mi + 1e-10f) + vl / (ml * ml + 1e-10f));
    int nt = 0;
    for (int e = 0; e < 8; ++e)
      for (int tt = 0; tt < (tot[e] + 255) >> 8; ++tt) {
        tmap[nt] = e; tmap[MAXT + nt] = tt; ++nt;
      }
    for (; nt < MAXT; ++nt) tmap[nt] = -1;
  }
  __syncthreads();
  for (int i = 0; i < 32; ++i) {
    int idx = t * 32 + i;
    int e = tidx[idx];
    int slot = off[e] + hcnt[t][e];
    hcnt[t][e] += 1;
    row_ids[slot] = idx >> 1;
    pos[idx] = slot;
  }
}

// ---------------------------------------------- W [E][K][N] f32 -> Wt [E][N][K] bf16
__global__ void transpose_cvt(const float* __restrict__ W, bf16* __restrict__ Wt,
                              int K, int N) {
  __shared__ bf16 tile[64][72];
  int e = blockIdx.z;
  int k0 = blockIdx.y * 64, n0 = blockIdx.x * 64;
  const float* Wp = W + (size_t)e * K * N;
  bf16* Wtp = Wt + (size_t)e * N * K;
  int t = threadIdx.x;
  int cr = t >> 4;
  int cc = (t & 15) * 4;
  #pragma unroll
  for (int p = 0; p < 4; ++p) {
    int kr = cr + p * 16;
    float4 v = *(const float4*)(Wp + (size_t)(k0 + kr) * N + n0 + cc);
    tile[cc + 0][kr] = __float2bfloat16(v.x);
    tile[cc + 1][kr] = __float2bfloat16(v.y);
    tile[cc + 2][kr] = __float2bfloat16(v.z);
    tile[cc + 3][kr] = __float2bfloat16(v.w);
  }
  __syncthreads();
  #pragma unroll
  for (int p = 0; p < 2; ++p) {
    int o = p * 256 + t;
    int n = o >> 3, k8 = (o & 7) * 8;
    v8s val = *(const v8s*)&tile[n][k8];
    *(v8s*)(Wtp + (size_t)(n0 + n) * K + k0 + k8) = val;
  }
}

// ---------------------------------------------------------------- grouped GEMM
// 256x256 tile, 512 threads (2M x 4N waves, wave-tile 128x64), BK=64, 2 K-tile
// LDS dbuf, 4 phases per K-tile: {ds_read frags; stage next A (q0) / B (q1);
// lgkmcnt(0); setprio(1) 16 MFMA setprio(0)}; one vmcnt(0)+s_barrier per
// K-tile at q3 (2-3 phase issue-to-drain distance).  XOR-(row&7) swizzle
// (verified R2-R5).  GEMM1: gridDim.x=8 => colb==XCD id (B-panel L2-locality).
template<int KDIM, bool GATHER, bool GELU, bool COLX>
__global__ __launch_bounds__(512, 2)
void gemm_mlp(const bf16* __restrict__ Ab, const bf16* __restrict__ Wt,
              const float* __restrict__ bias, bf16* __restrict__ Outb,
              const int* __restrict__ row_ids, const int* __restrict__ cnt_off,
              const int* __restrict__ tmap, const int N) {
  constexpr int BK = 64, BM = 256, BN = 256;
  constexpr int NK = KDIM / BK;
  static_assert(NK % 2 == 0 && NK >= 4, "NK even, >=4");
  __shared__ __align__(16) bf16 lds[2][(BM + BN) * BK];   // 2 x 64 KiB
  const int cb = COLX ? blockIdx.x : blockIdx.y;
  const int ti = COLX ? blockIdx.y : blockIdx.x;
  const int e = tmap[ti];
  if (e < 0) return;
  const int rowb = tmap[MAXT + ti];
  const int cnt = cnt_off[e];
  const int off = cnt_off[8 + e];
  const int t = (int)threadIdx.x, w = t >> 6, l = t & 63;
  const int cs = (l & 7) ^ (l >> 3);    // pre-swizzled source chunk col
  const bf16* gA[4];
  const bf16* gB[4];
  #pragma unroll
  for (int it = 0; it < 4; ++it) {
    int rt = (it * 8 + w) * 8 + (l >> 3);
    int r = rowb * BM + rt;
    int rc = r < cnt ? r : cnt - 1;
    long arow = GATHER ? (long)row_ids[off + rc] : (long)(off + rc);
    gA[it] = Ab + arow * (long)KDIM + cs * 8;
    gB[it] = Wt + ((size_t)e * N + (size_t)cb * BN + rt) * KDIM + cs * 8;
  }
  v4f acc[8][4] = {};
  const int wm = w >> 2, wn = w & 3;    // 2 x 4 wave grid

#define STAGE_A(b, k0) do {                                                 \
    _Pragma("unroll")                                                       \
    for (int it = 0; it < 4; ++it)                                          \
      gl_lds16(gA[it] + (k0), &lds[b][(it * 8 + w) * 512]);                 \
  } while (0)
#define STAGE_B(b, k0) do {                                                 \
    _Pragma("unroll")                                                       \
    for (int it = 0; it < 4; ++it)                                          \
      gl_lds16(gB[it] + (k0), &lds[b][BM * BK + (it * 8 + w) * 512]);       \
  } while (0)

#define READ_A(b, fm, kk) (*(const v8s*)(&lds[b][0] +                       \
    (wm * 128 + (fm) * 16 + (l & 15)) * 64 +                                \
    ((((kk) * 4 + (l >> 4)) ^ (l & 7)) << 3)))
#define READ_B(b, fn, kk) (*(const v8s*)(&lds[b][BM * BK] +                 \
    (wn * 64 + (fn) * 16 + (l & 15)) * 64 +                                 \
    ((((kk) * 4 + (l >> 4)) ^ (l & 7)) << 3)))

#define SB    __builtin_amdgcn_sched_barrier(0)
#define BARR  __builtin_amdgcn_s_barrier()
#define LGKM0 asm volatile("s_waitcnt lgkmcnt(0)" ::: "memory")
#define VM0   asm volatile("s_waitcnt vmcnt(0)" ::: "memory")

#define MFMA8(fmb, fm2)                                                     \
    _Pragma("unroll")                                                       \
    for (int fn = 0; fn < 4; ++fn)                                          \
      _Pragma("unroll")                                                     \
      for (int kk = 0; kk < 2; ++kk)                                        \
        acc[(fmb) + (fm2)][fn] = __builtin_amdgcn_mfma_f32_16x16x32_bf16(   \
            af[fm2][kk], bfr[fn][kk], acc[(fmb) + (fm2)][fn], 0, 0, 0);

#define TILE(b, nb, knext) do {                                             \
    v8s bfr[4][2];                                                          \
    { /* q0: B frags + A fm0,1; stage next A */                             \
      v8s af[2][2];                                                         \
      _Pragma("unroll")                                                     \
      for (int fn = 0; fn < 4; ++fn) {                                      \
        bfr[fn][0] = READ_B(b, fn, 0); bfr[fn][1] = READ_B(b, fn, 1);       \
      }                                                                     \
      af[0][0] = READ_A(b, 0, 0); af[0][1] = READ_A(b, 0, 1);               \
      af[1][0] = READ_A(b, 1, 0); af[1][1] = READ_A(b, 1, 1);               \
      if ((knext) < KDIM) STAGE_A(nb, knext);                               \
      LGKM0; SB;                                                            \
      __builtin_amdgcn_s_setprio(1); MFMA8(0, 0) MFMA8(0, 1)                \
      __builtin_amdgcn_s_setprio(0);                                        \
    }                                                                       \
    { /* q1: A fm2,3; stage next B */                                       \
      v8s af[2][2];                                                         \
      af[0][0] = READ_A(b, 2, 0); af[0][1] = READ_A(b, 2, 1);               \
      af[1][0] = READ_A(b, 3, 0); af[1][1] = READ_A(b, 3, 1);               \
      if ((knext) < KDIM) STAGE_B(nb, knext);                               \
      LGKM0; SB;                                                            \
      __builtin_amdgcn_s_setprio(1); MFMA8(2, 0) MFMA8(2, 1)                \
      __builtin_amdgcn_s_setprio(0);                                        \
    }                                                                       \
    { /* q2: A fm4,5 */                                                     \
      v8s af[2][2];                                                         \
      af[0][0] = READ_A(b, 4, 0); af[0][1] = READ_A(b, 4, 1);               \
      af[1][0] = READ_A(b, 5, 0); af[1][1] = READ_A(b, 5, 1);               \
      LGKM0; SB;                                                            \
      __builtin_amdgcn_s_setprio(1); MFMA8(4, 0) MFMA8(4, 1)                \
      __builtin_amdgcn_s_setprio(0);                                        \
    }                                                                       \
    { /* q3: A fm6,7; then confirm next tile */                             \
      v8s af[2][2];                                                         \
      af[0][0] = READ_A(b, 6, 0); af[0][1] = READ_A(b, 6, 1);               \
      af[1][0] = READ_A(b, 7, 0); af[1][1] = READ_A(b, 7, 1);               \
      LGKM0; SB;                                                            \
      __builtin_amdgcn_s_setprio(1); MFMA8(6, 0) MFMA8(6, 1)                \
      __builtin_amdgcn_s_setprio(0);                                        \
      VM0; SB; BARR; SB;                                                    \
    }                                                                       \
  } while (0)

  STAGE_A(0, 0); STAGE_B(0, 0);
  VM0; SB; BARR; SB;
  #pragma unroll 1
  for (int ks = 0; ks < NK; ks += 2) {
    TILE(0, 1, (ks + 1) * BK);
    TILE(1, 0, (ks + 2) * BK);
  }
#undef TILE
#undef MFMA8
#undef STAGE_A
#undef STAGE_B
#undef READ_A
#undef READ_B
#undef LGKM0
#undef VM0

  // ---- epilogue: per-wave LDS transpose -> bias(+gelu) -> coalesced 16B stores
  float* eps = (float*)(&lds[0][0]) + w * (16 * 68);   // 16 rows x 68 f32, wave-private
  const float* bp = bias + (size_t)e * N + (size_t)cb * BN + wn * 64 + (l & 7) * 8;
  float bv[8];
  #pragma unroll
  for (int jj = 0; jj < 8; ++jj) bv[jj] = bp[jj];
  #pragma unroll
  for (int fm = 0; fm < 8; ++fm) {
    #pragma unroll
    for (int fn = 0; fn < 4; ++fn)
      #pragma unroll
      for (int q = 0; q < 4; ++q)
        eps[((l >> 4) * 4 + q) * 68 + fn * 16 + (l & 15)] = acc[fm][fn][q];
    #pragma unroll
    for (int half = 0; half < 2; ++half) {
      int row = (l >> 3) + 8 * half;
      int r = rowb * BM + wm * 128 + fm * 16 + row;
      if (r < cnt) {
        const float* rp = eps + row * 68 + (l & 7) * 8;
        union { bf16 h[8]; uint4 u; } pk;
        #pragma unroll
        for (int jj = 0; jj < 8; ++jj) {
          float v = rp[jj] + bv[jj];
          if (GELU) {
            float u = 0.7978845608028654f * (v + 0.044715f * v * v * v);
            float th = 1.f - 2.f / (__expf(2.f * u) + 1.f);   // tanh(u)
            v = 0.5f * v * (1.f + th);
          }
          pk.h[jj] = __float2bfloat16(v);
        }
        *(uint4*)(Outb + (size_t)(off + r) * N + (size_t)cb * BN + wn * 64 + (l & 7) * 8) = pk.u;
      }
    }
  }
#undef SB
#undef BARR
}

// ---------------------------------------------------------------- combine
__global__ void combine_kernel(const bf16* __restrict__ z, const float* __restrict__ gates,
                               const int* __restrict__ pos, float* __restrict__ y) {
  int gt = blockIdx.x * 256 + threadIdx.x;
  int tok = gt >> 6, l = gt & 63;
  if (tok >= B_TOK) return;
  const bf16* z1 = z + (size_t)pos[2 * tok] * D_OUT;
  const bf16* z2 = z + (size_t)pos[2 * tok + 1] * D_OUT;
  float g1 = gates[2 * tok], g2 = gates[2 * tok + 1];
  float a[12], b[12];
  float m1 = -1e30f, m2 = -1e30f;
  #pragma unroll
  for (int i = 0; i < 12; ++i) {
    a[i] = __bfloat162float(z1[l + 64 * i]);
    b[i] = __bfloat162float(z2[l + 64 * i]);
    m1 = fmaxf(m1, a[i]); m2 = fmaxf(m2, b[i]);
  }
  #pragma unroll
  for (int d = 1; d < 64; d <<= 1) {
    m1 = fmaxf(m1, __shfl_xor(m1, d));
    m2 = fmaxf(m2, __shfl_xor(m2, d));
  }
  float s1 = 0.f, s2 = 0.f;
  #pragma unroll
  for (int i = 0; i < 12; ++i) { s1 += __expf(a[i] - m1); s2 += __expf(b[i] - m2); }
  #pragma unroll
  for (int d = 1; d < 64; d <<= 1) { s1 += __shfl_xor(s1, d); s2 += __shfl_xor(s2, d); }
  float c1 = g1 / s1, c2 = g2 / s2;
  #pragma unroll
  for (int i = 0; i < 12; ++i) {
    float cmb = c1 * __expf(a[i] - m1) + c2 * __expf(b[i] - m2);
    y[(size_t)tok * D_OUT + l + 64 * i] = logf(cmb == 0.f ? 2.2204460492503131e-16f : cmb);
  }
}

// ---------------------------------------------------------------- launch
extern "C" void kernel_launch(void* const* d_in, const int* in_sizes, int n_in,
                              void* d_out, int out_size, void* d_ws, size_t ws_size,
                              hipStream_t stream) {
  const float* x  = (const float*)d_in[0];
  const float* wg = (const float*)d_in[1];
  const float* W1 = (const float*)d_in[2];
  const float* b1 = (const float*)d_in[3];
  const float* W2 = (const float*)d_in[4];
  const float* b2 = (const float*)d_in[5];
  float* out = (float*)d_out;

  char* ws = (char*)d_ws;
  int*   cnt_off = (int*)(ws + 0);                // [16]: counts then offsets
  float* gates   = (float*)(ws + 256);            // 4096*2 f32
  int*   tidx    = (int*)(ws + 256 + 32768);
  int*   pos     = (int*)(ws + 256 + 65536);
  int*   row_ids = (int*)(ws + 256 + 98304);
  int*   tmap    = (int*)(ws + 256 + 131072);     // [2*MAXT]
  const size_t base = 262144;
  bf16* x_bf = (bf16*)(ws + base);                        //  6,291,456 B
  bf16* W1t  = (bf16*)(ws + base + 6291456);              // 25,165,824 B
  bf16* W2t  = (bf16*)(ws + base + 31457280);             // 25,165,824 B
  bf16* h_bf = (bf16*)(ws + base + 56623104);             // 33,554,432 B
  bf16* z_bf = (bf16*)(ws + base);                        // aliases x_bf/W1t (dead by GEMM2)

  transpose_cvt<<<dim3(D_H / 64,  D_IN / 64, E_EXP), 256, 0, stream>>>(W1, W1t, D_IN, D_H);
  transpose_cvt<<<dim3(D_OUT / 64, D_H / 64, E_EXP), 256, 0, stream>>>(W2, W2t, D_H, D_OUT);
  gate_cvt_kernel<<<dim3(1024), 256, 0, stream>>>(x, wg, x_bf, gates, tidx);
  finalize_kernel<<<dim3(1), 256, 0, stream>>>(tidx, gates, cnt_off, row_ids, pos, tmap,
                                               out + (size_t)B_TOK * D_OUT);
  // GEMM1: gridDim.x = 8 = #XCDs -> colb == XCD id (B-panel stays in own-XCD L2)
  gemm_mlp<D_IN, true,  true,  true ><<<dim3(D_H / 256, MAXT), 512, 0, stream>>>(
      x_bf, W1t, b1, h_bf, row_ids, cnt_off, tmap, D_H);
  // GEMM2: mt-major (consecutive blocks share the same B col-panel)
  gemm_mlp<D_H,  false, false, false><<<dim3(MAXT, D_OUT / 256), 512, 0, stream>>>(
      h_bf, W2t, b2, z_bf, row_ids, cnt_off, tmap, D_OUT);
  combine_kernel<<<dim3(1024), 256, 0, stream>>>(z_bf, gates, pos, out);
}

// Round 8
// 161.227 us; speedup vs baseline: 1.0202x; 1.0202x over previous
//
#include <hip/hip_runtime.h>
#include <hip/hip_bf16.h>
#include <math.h>

typedef __hip_bfloat16 bf16;
typedef short v8s __attribute__((ext_vector_type(8)));
typedef float v4f __attribute__((ext_vector_type(4)));

#define B_TOK 4096
#define E_EXP 8
#define D_IN  768
#define D_H   2048
#define D_OUT 768
#define MAXT  72      // max M-tiles of 128 over all experts (64 + 7 skew, padded)

// ---------------------------------------------------------------- helpers
__device__ __forceinline__ void gl_lds16(const bf16* g, bf16* l) {
  __builtin_amdgcn_global_load_lds(
      (const __attribute__((address_space(1))) unsigned int*)g,
      (__attribute__((address_space(3))) unsigned int*)l, 16, 0, 0);
}

// ---------------------------------------------------------------- fused prep:
// blocks [0,3072): W1 transpose; [3072,6144): W2 transpose; [6144,7168): gate+cvt.
// All independent -> one launch, full-chip overlap.
__global__ __launch_bounds__(256)
void prep_kernel(const float* __restrict__ x, const float* __restrict__ wg,
                 const float* __restrict__ W1, const float* __restrict__ W2,
                 bf16* __restrict__ W1t, bf16* __restrict__ W2t,
                 bf16* __restrict__ xb, float* __restrict__ gates,
                 int* __restrict__ tidx) {
  __shared__ bf16 tile[64][72];
  const int b = blockIdx.x;
  const int t = threadIdx.x;
  if (b < 6144) {
    // ---- transpose W [E][K][N] f32 -> Wt [E][N][K] bf16 (64x64 tile)
    const float* W; bf16* Wt; int K, N, bx, by, bz;
    if (b < 3072) {
      W = W1; Wt = W1t; K = D_IN; N = D_H;
      bx = b % 32; by = (b / 32) % 12; bz = b / 384;
    } else {
      int c = b - 3072;
      W = W2; Wt = W2t; K = D_H; N = D_OUT;
      bx = c % 12; by = (c / 12) % 32; bz = c / 384;
    }
    int k0 = by * 64, n0 = bx * 64;
    const float* Wp = W + (size_t)bz * K * N;
    bf16* Wtp = Wt + (size_t)bz * N * K;
    int cr = t >> 4;
    int cc = (t & 15) * 4;
    #pragma unroll
    for (int p = 0; p < 4; ++p) {
      int kr = cr + p * 16;
      float4 v = *(const float4*)(Wp + (size_t)(k0 + kr) * N + n0 + cc);
      tile[cc + 0][kr] = __float2bfloat16(v.x);
      tile[cc + 1][kr] = __float2bfloat16(v.y);
      tile[cc + 2][kr] = __float2bfloat16(v.z);
      tile[cc + 3][kr] = __float2bfloat16(v.w);
    }
    __syncthreads();
    #pragma unroll
    for (int p = 0; p < 2; ++p) {
      int o = p * 256 + t;
      int n = o >> 3, k8 = (o & 7) * 8;
      v8s val = *(const v8s*)&tile[n][k8];
      *(v8s*)(Wtp + (size_t)(n0 + n) * K + k0 + k8) = val;
    }
  } else {
    // ---- gate + x->bf16 (1 wave per token)
    int gt = (b - 6144) * 256 + t;
    int tok = gt >> 6, l = gt & 63;
    const float* xr = x + (size_t)tok * D_IN;
    bf16* xbr = xb + (size_t)tok * D_IN;
    float acc[8] = {0.f,0.f,0.f,0.f,0.f,0.f,0.f,0.f};
    #pragma unroll
    for (int i = 0; i < 3; ++i) {
      int k0 = i * 256 + l * 4;
      float4 v = *(const float4*)(xr + k0);
      union { bf16 h[4]; uint2 u; } pk;
      pk.h[0] = __float2bfloat16(v.x); pk.h[1] = __float2bfloat16(v.y);
      pk.h[2] = __float2bfloat16(v.z); pk.h[3] = __float2bfloat16(v.w);
      *(uint2*)(xbr + k0) = pk.u;
      float xv[4] = {v.x, v.y, v.z, v.w};
      #pragma unroll
      for (int j = 0; j < 4; ++j) {
        const float* wr = wg + (size_t)(k0 + j) * 8;
        float4 w0 = *(const float4*)wr;
        float4 w1 = *(const float4*)(wr + 4);
        acc[0] += xv[j] * w0.x; acc[1] += xv[j] * w0.y;
        acc[2] += xv[j] * w0.z; acc[3] += xv[j] * w0.w;
        acc[4] += xv[j] * w1.x; acc[5] += xv[j] * w1.y;
        acc[6] += xv[j] * w1.z; acc[7] += xv[j] * w1.w;
      }
    }
    #pragma unroll
    for (int d = 1; d < 64; d <<= 1)
      #pragma unroll
      for (int e = 0; e < 8; ++e) acc[e] += __shfl_xor(acc[e], d);
    if (l == 0) {
      int i1 = 0; float v1 = acc[0];
      #pragma unroll
      for (int e = 1; e < 8; ++e) if (acc[e] > v1) { v1 = acc[e]; i1 = e; }
      int i2 = -1; float v2 = -1e30f;
      #pragma unroll
      for (int e = 0; e < 8; ++e) if (e != i1 && acc[e] > v2) { v2 = acc[e]; i2 = e; }
      float ex = __expf(v2 - v1);
      float g1 = 1.f / (1.f + ex), g2 = ex / (1.f + ex);
      gates[2 * tok] = g1; gates[2 * tok + 1] = g2;
      tidx[2 * tok] = i1;  tidx[2 * tok + 1] = i2;
    }
  }
}

// ---------------------------------------------- single-block: histogram + scan +
// slot assignment + counts/offsets + tile map + aux loss.  256 threads.
__global__ void finalize_kernel(const int* __restrict__ tidx, const float* __restrict__ gates,
                                int* __restrict__ cnt_off, int* __restrict__ row_ids,
                                int* __restrict__ pos, int* __restrict__ tmap,
                                float* __restrict__ loss_out) {
  __shared__ int   hcnt[256][9];
  __shared__ float himp[256][9];
  __shared__ int   tot[8], off[8];
  __shared__ float itot[8];
  int t = threadIdx.x;
  #pragma unroll
  for (int e = 0; e < 8; ++e) { hcnt[t][e] = 0; himp[t][e] = 0.f; }
  __syncthreads();
  for (int i = 0; i < 32; ++i) {
    int idx = t * 32 + i;
    int e = tidx[idx];
    hcnt[t][e] += 1;
    himp[t][e] += gates[idx];
  }
  __syncthreads();
  if (t < 8) {
    int run = 0; float s = 0.f;
    for (int j = 0; j < 256; ++j) {
      int c = hcnt[j][t];
      hcnt[j][t] = run;
      run += c;
      s += himp[j][t];
    }
    tot[t] = run; itot[t] = s;
  }
  __syncthreads();
  if (t == 0) {
    int o = 0;
    float mi = 0.f, ml = 0.f;
    for (int e = 0; e < 8; ++e) {
      off[e] = o; o += tot[e];
      cnt_off[e] = tot[e]; cnt_off[8 + e] = off[e];
      mi += itot[e]; ml += (float)tot[e];
    }
    mi *= 0.125f; ml *= 0.125f;
    float vi = 0.f, vl = 0.f;
    for (int e = 0; e < 8; ++e) {
      float d = itot[e] - mi;        vi += d * d;
      float d2 = (float)tot[e] - ml; vl += d2 * d2;
    }
    vi /= 7.f; vl /= 7.f;
    *loss_out = 0.01f * (vi / (mi * mi + 1e-10f) + vl / (ml * ml + 1e-10f));
    int nt = 0;
    for (int e = 0; e < 8; ++e)
      for (int tt = 0; tt < (tot[e] + 127) >> 7; ++tt) {
        tmap[nt] = e; tmap[MAXT + nt] = tt; ++nt;
      }
    for (; nt < MAXT; ++nt) tmap[nt] = -1;
  }
  __syncthreads();
  for (int i = 0; i < 32; ++i) {
    int idx = t * 32 + i;
    int e = tidx[idx];
    int slot = off[e] + hcnt[t][e];
    hcnt[t][e] += 1;
    row_ids[slot] = idx >> 1;
    pos[idx] = slot;
  }
}

// ---------------------------------------------------------------- GEMM1 (R6-proven)
// 128x128 tile, BK=64, 256 threads (2x2 waves), 2-buffer counted-vmcnt(8),
// 64 KiB LDS -> 2 blocks/CU.  XOR-(row&7) chunk swizzle (verified R2-R6).
template<int KDIM, bool GATHER, bool GELU>
__global__ __launch_bounds__(256, 2)
void gemm_mlp(const bf16* __restrict__ Ab, const bf16* __restrict__ Wt,
              const float* __restrict__ bias, bf16* __restrict__ Outb,
              const int* __restrict__ row_ids, const int* __restrict__ cnt_off,
              const int* __restrict__ tmap, const int N) {
  constexpr int BK = 64, BM = 128, BN = 128;
  constexpr int NK = KDIM / BK;
  static_assert(NK % 2 == 0 && NK >= 4, "NK even, >=4");
  __shared__ __align__(16) bf16 lds[2][(BM + BN) * BK];   // 2 x 32 KiB
  const int ti = blockIdx.y;
  const int e = tmap[ti];
  if (e < 0) return;
  const int rowb = tmap[MAXT + ti];
  const int cnt = cnt_off[e];
  const int off = cnt_off[8 + e];
  const int colb = blockIdx.x;
  const int t = (int)threadIdx.x, w = t >> 6, l = t & 63;
  const int cs = (l & 7) ^ (l >> 3);    // pre-swizzled source chunk col
  const bf16* gA[4];
  const bf16* gB[4];
  #pragma unroll
  for (int it = 0; it < 4; ++it) {
    int rt = (it * 4 + w) * 8 + (l >> 3);
    int r = rowb * BM + rt;
    int rc = r < cnt ? r : cnt - 1;
    long arow = GATHER ? (long)row_ids[off + rc] : (long)(off + rc);
    gA[it] = Ab + arow * (long)KDIM + cs * 8;
  }
  #pragma unroll
  for (int it = 0; it < 4; ++it) {
    int rt = (it * 4 + w) * 8 + (l >> 3);
    gB[it] = Wt + ((size_t)e * N + (size_t)colb * BN + rt) * KDIM + cs * 8;
  }
  v4f acc[4][4] = {};
  const int wm = w >> 1, wn = w & 1;    // 2 x 2 wave grid

#define STAGE(b, k0) do {                                                   \
    _Pragma("unroll")                                                       \
    for (int it = 0; it < 4; ++it)                                          \
      gl_lds16(gA[it] + (k0), &lds[b][(it * 4 + w) * 512]);                 \
    _Pragma("unroll")                                                       \
    for (int it = 0; it < 4; ++it)                                          \
      gl_lds16(gB[it] + (k0), &lds[b][BM * BK + (it * 4 + w) * 512]);       \
  } while (0)

#define COMPUTE(b) do {                                                     \
    __builtin_amdgcn_s_setprio(1);                                          \
    _Pragma("unroll")                                                       \
    for (int kk = 0; kk < 2; ++kk) {                                        \
      v8s af[4], bfr[4];                                                    \
      _Pragma("unroll")                                                     \
      for (int fm = 0; fm < 4; ++fm) {                                      \
        int row = wm * 64 + fm * 16 + (l & 15);                             \
        int cg = kk * 4 + (l >> 4);                                         \
        af[fm] = *(const v8s*)(&lds[b][0] + row * BK + ((cg ^ (row & 7)) << 3)); \
      }                                                                     \
      _Pragma("unroll")                                                     \
      for (int fn = 0; fn < 4; ++fn) {                                      \
        int row = wn * 64 + fn * 16 + (l & 15);                             \
        int cg = kk * 4 + (l >> 4);                                         \
        bfr[fn] = *(const v8s*)(&lds[b][BM * BK] + row * BK + ((cg ^ (row & 7)) << 3)); \
      }                                                                     \
      _Pragma("unroll")                                                     \
      for (int fm = 0; fm < 4; ++fm)                                        \
        _Pragma("unroll")                                                   \
        for (int fn = 0; fn < 4; ++fn)                                      \
          acc[fm][fn] = __builtin_amdgcn_mfma_f32_16x16x32_bf16(af[fm], bfr[fn], acc[fm][fn], 0, 0, 0); \
    }                                                                       \
    __builtin_amdgcn_s_setprio(0);                                          \
  } while (0)

#define SB    __builtin_amdgcn_sched_barrier(0)
#define BARR  __builtin_amdgcn_s_barrier()
#define WAIT8 asm volatile("s_waitcnt vmcnt(8)" ::: "memory")
#define WAITZ asm volatile("s_waitcnt vmcnt(0)" ::: "memory")

  STAGE(0, 0);
  #pragma unroll 1
  for (int ks = 0; ks < NK - 2; ks += 2) {
    STAGE(1, (ks + 1) * BK);
    WAIT8; SB; BARR; SB;
    COMPUTE(0);
    BARR; SB;
    STAGE(0, (ks + 2) * BK);
    WAIT8; SB; BARR; SB;
    COMPUTE(1);
    BARR; SB;
  }
  STAGE(1, (NK - 1) * BK);
  WAIT8; SB; BARR; SB;
  COMPUTE(0);
  WAITZ; SB; BARR; SB;
  COMPUTE(1);
  BARR; SB;                      // protect epilogue LDS reuse
#undef STAGE
#undef COMPUTE
#undef WAIT8
#undef WAITZ

  // ---- epilogue: per-wave LDS transpose -> bias(+gelu) -> coalesced 16B stores
  float* eps = (float*)(&lds[0][0]) + w * (16 * 68);
  const float* bp = bias + (size_t)e * N + (size_t)colb * BN + wn * 64 + (l & 7) * 8;
  float bv[8];
  #pragma unroll
  for (int jj = 0; jj < 8; ++jj) bv[jj] = bp[jj];
  #pragma unroll
  for (int fm = 0; fm < 4; ++fm) {
    #pragma unroll
    for (int fn = 0; fn < 4; ++fn)
      #pragma unroll
      for (int q = 0; q < 4; ++q)
        eps[((l >> 4) * 4 + q) * 68 + fn * 16 + (l & 15)] = acc[fm][fn][q];
    #pragma unroll
    for (int half = 0; half < 2; ++half) {
      int row = (l >> 3) + 8 * half;
      int r = rowb * BM + wm * 64 + fm * 16 + row;
      if (r < cnt) {
        const float* rp = eps + row * 68 + (l & 7) * 8;
        union { bf16 h[8]; uint4 u; } pk;
        #pragma unroll
        for (int jj = 0; jj < 8; ++jj) {
          float v = rp[jj] + bv[jj];
          if (GELU) {
            float u = 0.7978845608028654f * (v + 0.044715f * v * v * v);
            float th = 1.f - 2.f / (__expf(2.f * u) + 1.f);   // tanh(u)
            v = 0.5f * v * (1.f + th);
          }
          pk.h[jj] = __float2bfloat16(v);
        }
        *(uint4*)(Outb + (size_t)(off + r) * N + (size_t)colb * BN + wn * 64 + (l & 7) * 8) = pk.u;
      }
    }
  }
#undef SB
#undef BARR
}

// ---------------------------------------------------------------- GEMM2: BK=32
// 128x128 tile, BK=32, 256 threads, 2-buffer counted-vmcnt(4), 32 KiB LDS ->
// 3 blocks/CU.  Chunk swizzle p = c ^ ((row>>1)&3): bank-uniform on 64B rows
// (roundtrip: stored g(R,p) = p ^ ((R>>1)&3); read p = (l>>4)^((R>>1)&3)).
template<int KDIM, bool GELU>
__global__ __launch_bounds__(256, 3)
void gemm_bk32(const bf16* __restrict__ Ab, const bf16* __restrict__ Wt,
               const float* __restrict__ bias, bf16* __restrict__ Outb,
               const int* __restrict__ cnt_off, const int* __restrict__ tmap,
               const int N) {
  constexpr int BK = 32, BM = 128, BN = 128;
  constexpr int NK = KDIM / BK;
  static_assert(NK % 2 == 0 && NK >= 4, "NK even, >=4");
  __shared__ __align__(16) bf16 lds[2][(BM + BN) * BK];   // 2 x 16 KiB
  const int ti = blockIdx.y;
  const int e = tmap[ti];
  if (e < 0) return;
  const int rowb = tmap[MAXT + ti];
  const int cnt = cnt_off[e];
  const int off = cnt_off[8 + e];
  const int colb = blockIdx.x;
  const int t = (int)threadIdx.x, w = t >> 6, l = t & 63;
  const int cs = (l & 3) ^ ((l >> 3) & 3);   // pre-swizzled source chunk (of 4)
  const bf16* gA[2];
  const bf16* gB[2];
  #pragma unroll
  for (int it = 0; it < 2; ++it) {
    int rt = (it * 4 + w) * 16 + (l >> 2);   // slab*16 + row-in-slab
    int r = rowb * BM + rt;
    int rc = r < cnt ? r : cnt - 1;
    gA[it] = Ab + (long)(off + rc) * KDIM + cs * 8;
    gB[it] = Wt + ((size_t)e * N + (size_t)colb * BN + rt) * KDIM + cs * 8;
  }
  v4f acc[4][4] = {};
  const int wm = w >> 1, wn = w & 1;

#define STAGE(b, k0) do {                                                   \
    _Pragma("unroll")                                                       \
    for (int it = 0; it < 2; ++it)                                          \
      gl_lds16(gA[it] + (k0), &lds[b][(it * 4 + w) * 512]);                 \
    _Pragma("unroll")                                                       \
    for (int it = 0; it < 2; ++it)                                          \
      gl_lds16(gB[it] + (k0), &lds[b][BM * BK + (it * 4 + w) * 512]);       \
  } while (0)

// read: physical chunk p = (l>>4) ^ ((l>>1)&3)  (row low bits = l&15)
#define COMPUTE(b) do {                                                     \
    __builtin_amdgcn_s_setprio(1);                                          \
    v8s af[4], bfr[4];                                                      \
    const int p = (l >> 4) ^ ((l >> 1) & 3);                                \
    _Pragma("unroll")                                                       \
    for (int fm = 0; fm < 4; ++fm) {                                        \
      int row = wm * 64 + fm * 16 + (l & 15);                               \
      af[fm] = *(const v8s*)(&lds[b][0] + row * BK + p * 8);                \
    }                                                                       \
    _Pragma("unroll")                                                       \
    for (int fn = 0; fn < 4; ++fn) {                                        \
      int row = wn * 64 + fn * 16 + (l & 15);                               \
      bfr[fn] = *(const v8s*)(&lds[b][BM * BK] + row * BK + p * 8);         \
    }                                                                       \
    _Pragma("unroll")                                                       \
    for (int fm = 0; fm < 4; ++fm)                                          \
      _Pragma("unroll")                                                     \
      for (int fn = 0; fn < 4; ++fn)                                        \
        acc[fm][fn] = __builtin_amdgcn_mfma_f32_16x16x32_bf16(af[fm], bfr[fn], acc[fm][fn], 0, 0, 0); \
    __builtin_amdgcn_s_setprio(0);                                          \
  } while (0)

#define SB    __builtin_amdgcn_sched_barrier(0)
#define BARR  __builtin_amdgcn_s_barrier()
#define WAIT4 asm volatile("s_waitcnt vmcnt(4)" ::: "memory")
#define WAITZ asm volatile("s_waitcnt vmcnt(0)" ::: "memory")

  STAGE(0, 0);
  #pragma unroll 1
  for (int ks = 0; ks < NK - 2; ks += 2) {
    STAGE(1, (ks + 1) * BK);
    WAIT4; SB; BARR; SB;
    COMPUTE(0);
    BARR; SB;
    STAGE(0, (ks + 2) * BK);
    WAIT4; SB; BARR; SB;
    COMPUTE(1);
    BARR; SB;
  }
  STAGE(1, (NK - 1) * BK);
  WAIT4; SB; BARR; SB;
  COMPUTE(0);
  WAITZ; SB; BARR; SB;
  COMPUTE(1);
  BARR; SB;                      // protect epilogue LDS reuse
#undef STAGE
#undef COMPUTE
#undef WAIT4
#undef WAITZ

  // ---- epilogue: per-wave LDS transpose -> bias(+gelu) -> coalesced 16B stores
  float* eps = (float*)(&lds[0][0]) + w * (16 * 68);
  const float* bp = bias + (size_t)e * N + (size_t)colb * BN + wn * 64 + (l & 7) * 8;
  float bv[8];
  #pragma unroll
  for (int jj = 0; jj < 8; ++jj) bv[jj] = bp[jj];
  #pragma unroll
  for (int fm = 0; fm < 4; ++fm) {
    #pragma unroll
    for (int fn = 0; fn < 4; ++fn)
      #pragma unroll
      for (int q = 0; q < 4; ++q)
        eps[((l >> 4) * 4 + q) * 68 + fn * 16 + (l & 15)] = acc[fm][fn][q];
    #pragma unroll
    for (int half = 0; half < 2; ++half) {
      int row = (l >> 3) + 8 * half;
      int r = rowb * BM + wm * 64 + fm * 16 + row;
      if (r < cnt) {
        const float* rp = eps + row * 68 + (l & 7) * 8;
        union { bf16 h[8]; uint4 u; } pk;
        #pragma unroll
        for (int jj = 0; jj < 8; ++jj) {
          float v = rp[jj] + bv[jj];
          if (GELU) {
            float u = 0.7978845608028654f * (v + 0.044715f * v * v * v);
            float th = 1.f - 2.f / (__expf(2.f * u) + 1.f);
            v = 0.5f * v * (1.f + th);
          }
          pk.h[jj] = __float2bfloat16(v);
        }
        *(uint4*)(Outb + (size_t)(off + r) * N + (size_t)colb * BN + wn * 64 + (l & 7) * 8) = pk.u;
      }
    }
  }
#undef SB
#undef BARR
}

// ---------------------------------------------------------------- combine
__global__ void combine_kernel(const bf16* __restrict__ z, const float* __restrict__ gates,
                               const int* __restrict__ pos, float* __restrict__ y) {
  int gt = blockIdx.x * 256 + threadIdx.x;
  int tok = gt >> 6, l = gt & 63;
  if (tok >= B_TOK) return;
  const bf16* z1 = z + (size_t)pos[2 * tok] * D_OUT;
  const bf16* z2 = z + (size_t)pos[2 * tok + 1] * D_OUT;
  float g1 = gates[2 * tok], g2 = gates[2 * tok + 1];
  float a[12], b[12];
  float m1 = -1e30f, m2 = -1e30f;
  #pragma unroll
  for (int i = 0; i < 12; ++i) {
    a[i] = __bfloat162float(z1[l + 64 * i]);
    b[i] = __bfloat162float(z2[l + 64 * i]);
    m1 = fmaxf(m1, a[i]); m2 = fmaxf(m2, b[i]);
  }
  #pragma unroll
  for (int d = 1; d < 64; d <<= 1) {
    m1 = fmaxf(m1, __shfl_xor(m1, d));
    m2 = fmaxf(m2, __shfl_xor(m2, d));
  }
  float s1 = 0.f, s2 = 0.f;
  #pragma unroll
  for (int i = 0; i < 12; ++i) { s1 += __expf(a[i] - m1); s2 += __expf(b[i] - m2); }
  #pragma unroll
  for (int d = 1; d < 64; d <<= 1) { s1 += __shfl_xor(s1, d); s2 += __shfl_xor(s2, d); }
  float c1 = g1 / s1, c2 = g2 / s2;
  #pragma unroll
  for (int i = 0; i < 12; ++i) {
    float cmb = c1 * __expf(a[i] - m1) + c2 * __expf(b[i] - m2);
    y[(size_t)tok * D_OUT + l + 64 * i] = logf(cmb == 0.f ? 2.2204460492503131e-16f : cmb);
  }
}

// ---------------------------------------------------------------- launch
extern "C" void kernel_launch(void* const* d_in, const int* in_sizes, int n_in,
                              void* d_out, int out_size, void* d_ws, size_t ws_size,
                              hipStream_t stream) {
  const float* x  = (const float*)d_in[0];
  const float* wg = (const float*)d_in[1];
  const float* W1 = (const float*)d_in[2];
  const float* b1 = (const float*)d_in[3];
  const float* W2 = (const float*)d_in[4];
  const float* b2 = (const float*)d_in[5];
  float* out = (float*)d_out;

  char* ws = (char*)d_ws;
  int*   cnt_off = (int*)(ws + 0);                // [16]: counts then offsets
  float* gates   = (float*)(ws + 256);            // 4096*2 f32
  int*   tidx    = (int*)(ws + 256 + 32768);
  int*   pos     = (int*)(ws + 256 + 65536);
  int*   row_ids = (int*)(ws + 256 + 98304);
  int*   tmap    = (int*)(ws + 256 + 131072);     // [2*MAXT]
  const size_t base = 262144;
  bf16* x_bf = (bf16*)(ws + base);                        //  6,291,456 B
  bf16* W1t  = (bf16*)(ws + base + 6291456);              // 25,165,824 B
  bf16* W2t  = (bf16*)(ws + base + 31457280);             // 25,165,824 B
  bf16* h_bf = (bf16*)(ws + base + 56623104);             // 33,554,432 B
  bf16* z_bf = (bf16*)(ws + base);                        // aliases x_bf/W1t (dead by GEMM2)

  prep_kernel<<<dim3(7168), 256, 0, stream>>>(x, wg, W1, W2, W1t, W2t, x_bf, gates, tidx);
  finalize_kernel<<<dim3(1), 256, 0, stream>>>(tidx, gates, cnt_off, row_ids, pos, tmap,
                                               out + (size_t)B_TOK * D_OUT);
  gemm_mlp<D_IN, true, true><<<dim3(D_H / 128, MAXT), 256, 0, stream>>>(
      x_bf, W1t, b1, h_bf, row_ids, cnt_off, tmap, D_H);
  gemm_bk32<D_H, false><<<dim3(D_OUT / 128, MAXT), 256, 0, stream>>>(
      h_bf, W2t, b2, z_bf, cnt_off, tmap, D_OUT);
  combine_kernel<<<dim3(1024), 256, 0, stream>>>(z_bf, gates, pos, out);
}